// Round 6
// baseline (261.396 us; speedup 1.0000x reference)
//
#include <hip/hip_runtime.h>
#include <math.h>

#define B_   64
#define C_   64
#define D_   512
#define O_   256
#define G_   8
#define M_   4096

typedef __attribute__((ext_vector_type(8))) short s16x8;
typedef __attribute__((ext_vector_type(4))) float f32x4;
typedef unsigned short u16;
typedef unsigned int   u32;

__device__ __forceinline__ float bf2f(u16 u) { return __uint_as_float(((u32)u) << 16); }
__device__ __forceinline__ u16 f2bf(float f) {
    u32 u = __float_as_uint(f);
    return (u16)((u + 0x7FFFu + ((u >> 16) & 1u)) >> 16);
}
__device__ __forceinline__ void gload16(const void* g, void* l) {
    __builtin_amdgcn_global_load_lds((const __attribute__((address_space(1))) u32*)g,
                                     (__attribute__((address_space(3))) u32*)l, 16, 0, 0);
}
// bijective XCD swizzle for 256 logical units: consecutive nid share an XCD
__device__ __forceinline__ int swz256(int L) { return (L & 7) * 32 + (L >> 3); }

// device-scope sense-reversing grid barrier. bar[0]=count, bar[1]=generation.
// All 256 blocks are co-resident (1 block/CU). __threadfence() gives the
// device-scope release (L2 writeback) / acquire (L2 inv) around the barrier.
__device__ __forceinline__ void grid_barrier(u32* bar, int tid, int nb) {
    __syncthreads();                  // all block stores at least in our L2
    if (tid == 0) {
        __threadfence();              // writeback dirty L2 -> device scope
        u32 gen = __hip_atomic_load(bar + 1, __ATOMIC_RELAXED, __HIP_MEMORY_SCOPE_AGENT);
        u32 arrived = __hip_atomic_fetch_add(bar, 1u, __ATOMIC_ACQ_REL, __HIP_MEMORY_SCOPE_AGENT);
        if (arrived == (u32)nb - 1) {
            __hip_atomic_store(bar, 0u, __ATOMIC_RELAXED, __HIP_MEMORY_SCOPE_AGENT);
            __hip_atomic_fetch_add(bar + 1, 1u, __ATOMIC_RELEASE, __HIP_MEMORY_SCOPE_AGENT);
        } else {
            while (__hip_atomic_load(bar + 1, __ATOMIC_ACQUIRE, __HIP_MEMORY_SCOPE_AGENT) == gen)
                __builtin_amdgcn_s_sleep(8);
        }
        __threadfence();              // invalidate stale lines before next phase reads
    }
    __syncthreads();
}

#define SMEM_BYTES 69632   // 68 KB: max over phases (P3 = 67072 B)

__global__ __launch_bounds__(512)
void fused_kernel(const float* __restrict__ x, const float* __restrict__ W1,
                  const float* __restrict__ b1, const float* __restrict__ W2,
                  const float* __restrict__ b2, const float* __restrict__ Wg1,
                  const float* __restrict__ bg1, const float* __restrict__ Wg2,
                  const float* __restrict__ bg2, const int* __restrict__ region_indices,
                  float* __restrict__ out,
                  u16* __restrict__ x_bf, u16* __restrict__ W1t, u16* __restrict__ Wg1t,
                  u16* __restrict__ Wg2t, u16* __restrict__ a_bf, u16* __restrict__ bp_bf,
                  u16* __restrict__ m1_bf, u16* __restrict__ m2_bf,
                  float* __restrict__ adjw, u32* __restrict__ bar)
{
    __shared__ __align__(16) char sm[SMEM_BYTES];
    const int wg = blockIdx.x, tid = threadIdx.x;
    const int lane = tid & 63, w = tid >> 6;
    const int lr = lane & 15, lq = lane >> 4;
    const int sr = tid >> 3, ss = tid & 7, gsl = ss ^ (sr & 7);
    const int NB = 256;

    // ================= P0: x->bf16 cvt + W transposes =================
    {
        #pragma unroll
        for (int s = 0; s < 2; s++) {
            size_t i = ((size_t)(s * 256 + wg) * 512 + tid) * 8;
            const float4* p = (const float4*)(x + i);
            float4 v0 = p[0], v1 = p[1];
            s16x8 o;
            o[0]=(short)f2bf(v0.x); o[1]=(short)f2bf(v0.y); o[2]=(short)f2bf(v0.z); o[3]=(short)f2bf(v0.w);
            o[4]=(short)f2bf(v1.x); o[5]=(short)f2bf(v1.y); o[6]=(short)f2bf(v1.z); o[7]=(short)f2bf(v1.w);
            *(s16x8*)(x_bf + i) = o;
        }
        float (*tile)[32][33] = (float(*)[32][33])sm;      // 2 teams x 4.2 KB
        const int team = tid >> 8, t = tid & 255;
        const int tx = t & 31, ty = t >> 5;
        for (int u = 0; u < 2; u++) {
            int tile_id = wg * 2 + team + 512 * u;         // 0..1023, 896 real
            const float* src = nullptr; u16* dst = nullptr;
            int k0 = 0, n0 = 0, nsrc = 0, obase = 0;
            if (tile_id < 512) {            // W1 half h -> W1t rows [h*512..)
                int h = tile_id >> 8, tt = tile_id & 255;
                src = W1 + (size_t)h * 512 * 512; dst = W1t; obase = h * 512;
                k0 = (tt >> 4) * 32; n0 = (tt & 15) * 32; nsrc = 512;
            } else if (tile_id < 768) {     // Wg1
                int tt = tile_id - 512; src = Wg1; dst = Wg1t;
                k0 = (tt >> 4) * 32; n0 = (tt & 15) * 32; nsrc = 512;
            } else if (tile_id < 896) {     // Wg2
                int tt = tile_id - 768; src = Wg2; dst = Wg2t;
                k0 = (tt >> 3) * 32; n0 = (tt & 7) * 32; nsrc = 256;
            }
            if (src) {
                #pragma unroll
                for (int j = 0; j < 4; j++)
                    tile[team][ty + j * 8][tx] = src[(size_t)(k0 + ty + j * 8) * nsrc + n0 + tx];
            }
            __syncthreads();
            if (src) {
                #pragma unroll
                for (int j = 0; j < 4; j++)
                    dst[(size_t)(obase + n0 + ty + j * 8) * 512 + k0 + tx] =
                        f2bf(tile[team][tx][ty + j * 8]);
            }
            __syncthreads();
        }
    }
    grid_barrier(bar, tid, NB);

    // ================= P1: a|bp = x @ [W1a|W1b]  (128x128 tiles) =================
    {
        u16* As = (u16*)sm;                 // [2][8192]
        u16* Bs = (u16*)(sm + 32768);       // [2][8192]
        const int nid = swz256(wg);
        const int m0 = (nid >> 3) * 128, n0 = (nid & 7) * 128;
        const int wr = w >> 1, wc = w & 1;  // 4 x 2 waves
        f32x4 acc[2][4] = {};
        auto stage = [&](int buf, int kt) {
            #pragma unroll
            for (int ch = 0; ch < 2; ch++)
                gload16(x_bf + (size_t)(m0 + ch * 64 + sr) * 512 + kt + gsl * 8,
                        As + buf * 8192 + ch * 4096 + tid * 8);
            #pragma unroll
            for (int ch = 0; ch < 2; ch++)
                gload16(W1t + (size_t)(n0 + ch * 64 + sr) * 512 + kt + gsl * 8,
                        Bs + buf * 8192 + ch * 4096 + tid * 8);
        };
        stage(0, 0);
        int cur = 0;
        for (int t = 0; t < 8; t++) {
            __syncthreads();
            if (t < 7) stage(cur ^ 1, (t + 1) * 64);
            const u16* as = As + cur * 8192;
            const u16* bs = Bs + cur * 8192;
            #pragma unroll
            for (int ks = 0; ks < 2; ks++) {
                s16x8 af[2], bfv[4];
                #pragma unroll
                for (int m = 0; m < 2; m++) {
                    int r = wr * 32 + m * 16 + lr;
                    af[m] = *(const s16x8*)(as + r * 64 + (((ks * 4 + lq) ^ (r & 7)) * 8));
                }
                #pragma unroll
                for (int n = 0; n < 4; n++) {
                    int r = wc * 64 + n * 16 + lr;
                    bfv[n] = *(const s16x8*)(bs + r * 64 + (((ks * 4 + lq) ^ (r & 7)) * 8));
                }
                #pragma unroll
                for (int m = 0; m < 2; m++)
                    #pragma unroll
                    for (int n = 0; n < 4; n++)
                        acc[m][n] = __builtin_amdgcn_mfma_f32_16x16x32_bf16(af[m], bfv[n], acc[m][n], 0, 0, 0);
            }
            cur ^= 1;
        }
        #pragma unroll
        for (int m = 0; m < 2; m++)
            #pragma unroll
            for (int n = 0; n < 4; n++)
                #pragma unroll
                for (int j = 0; j < 4; j++) {
                    int row = m0 + wr * 32 + m * 16 + lq * 4 + j;
                    int col = n0 + wc * 64 + n * 16 + lr;
                    float v = acc[m][n][j];
                    if (col < 512) a_bf[(size_t)row * 512 + col] = f2bf(v);
                    else           bp_bf[(size_t)row * 512 + col - 512] = f2bf(v);
                }
    }
    grid_barrier(bar, tid, NB);

    // ================= P2: scores + softmax + m1 (4 WGs/batch) =================
    {
        u16* bp  = (u16*)sm;                // 64 KB
        int* ri  = (int*)(sm + 65536);
        int* rid = (int*)(sm + 65536 + 256);
        const int nid = swz256(wg);
        const int b = nid >> 2, q = nid & 3;
        #pragma unroll
        for (int it = 0; it < 8; it++)
            gload16(bp_bf + (size_t)b * 32768 + it * 4096 + tid * 8, bp + it * 4096 + tid * 8);
        if (tid < 64) { int c = region_indices[tid]; ri[tid] = c; rid[c] = tid >> 3; }

        const int d0 = lane * 8;
        float4 b1a = *(const float4*)(b1 + d0), b1b = *(const float4*)(b1 + d0 + 4);
        float4 w2a = *(const float4*)(W2 + d0), w2b = *(const float4*)(W2 + d0 + 4);
        float b1v[8] = { b1a.x, b1a.y, b1a.z, b1a.w, b1b.x, b1b.y, b1b.z, b1b.w };
        float w2v[8] = { w2a.x, w2a.y, w2a.z, w2a.w, w2b.x, w2b.y, w2b.z, w2b.w };
        const float bias2 = b2[0];
        __syncthreads();

        #pragma unroll
        for (int rr = 0; rr < 2; rr++) {
            const int i = q * 16 + w * 2 + rr;
            const int bi = b * 64 + i;
            const int r = rid[i];
            int mem[8];
            #pragma unroll
            for (int m = 0; m < 8; m++) mem[m] = ri[r * 8 + m];

            s16x8 a8 = *(const s16x8*)(a_bf + (size_t)bi * 512 + d0);
            float ai[8];
            #pragma unroll
            for (int t = 0; t < 8; t++) ai[t] = bf2f((u16)a8[t]) + b1v[t];

            float p[8];
            #pragma unroll
            for (int m = 0; m < 8; m++) {
                s16x8 bv = *(const s16x8*)(bp + mem[m] * 512 + d0);
                float s = 0.f;
                #pragma unroll
                for (int t = 0; t < 8; t++) {
                    float h = ai[t] + bf2f((u16)bv[t]);
                    s += fmaxf(h, 0.f) * w2v[t];
                }
                p[m] = s;
            }
            #pragma unroll
            for (int off = 32; off >= 1; off >>= 1)
                #pragma unroll
                for (int m = 0; m < 8; m++) p[m] += __shfl_xor(p[m], off);

            float scmax = -INFINITY;
            #pragma unroll
            for (int m = 0; m < 8; m++) {
                p[m] = (mem[m] == i) ? -INFINITY : p[m] + bias2;
                scmax = fmaxf(scmax, p[m]);
            }
            float esum = 0.f;
            #pragma unroll
            for (int m = 0; m < 8; m++) {
                p[m] = (mem[m] == i) ? 0.f : __expf(p[m] - scmax);
                esum += p[m];
            }
            const float inv = 1.f / esum;

            float accv[8] = {};
            #pragma unroll
            for (int m = 0; m < 8; m++) {
                p[m] *= inv;
                s16x8 xv = *(const s16x8*)(x_bf + ((size_t)(b * 64 + mem[m])) * 512 + d0);
                #pragma unroll
                for (int t = 0; t < 8; t++) accv[t] += p[m] * bf2f((u16)xv[t]);
            }
            s16x8 o;
            #pragma unroll
            for (int t = 0; t < 8; t++) o[t] = (short)f2bf(accv[t]);
            *(s16x8*)(m1_bf + (size_t)bi * 512 + d0) = o;
            if (lane < 8) adjw[(size_t)bi * 8 + lane] = p[lane];
        }
    }
    grid_barrier(bar, tid, NB);

    // ================= P3: x1 (LDS) + fused m2 (BM=64 batch, BN=128) =================
    {
        u16* As  = (u16*)sm;                // [2][4096]
        u16* Bs  = (u16*)(sm + 16384);      // [2][8192]
        u16* x1s = (u16*)(sm + 49152);      // 64 x 136
        int* ri  = (int*)(sm + 66560);
        int* rid = (int*)(sm + 66816);
        const int nid = swz256(wg);
        const int b = nid >> 2, n0 = (nid & 3) * 128, m0 = b * 64;
        const int wr = w >> 2, wc = w & 3;  // 2 x 4 waves
        if (tid < 64) { int c = region_indices[tid]; ri[tid] = c; rid[c] = tid >> 3; }

        f32x4 acc[2][2] = {};
        auto stage = [&](int buf, int kt) {
            gload16(m1_bf + (size_t)(m0 + sr) * 512 + kt + gsl * 8, As + buf * 4096 + tid * 8);
            #pragma unroll
            for (int ch = 0; ch < 2; ch++)
                gload16(Wg1t + (size_t)(n0 + ch * 64 + sr) * 512 + kt + gsl * 8,
                        Bs + buf * 8192 + ch * 4096 + tid * 8);
        };
        stage(0, 0);
        int cur = 0;
        for (int t = 0; t < 8; t++) {
            __syncthreads();
            if (t < 7) stage(cur ^ 1, (t + 1) * 64);
            const u16* as = As + cur * 4096;
            const u16* bs = Bs + cur * 8192;
            #pragma unroll
            for (int ks = 0; ks < 2; ks++) {
                s16x8 af[2], bfv[2];
                #pragma unroll
                for (int m = 0; m < 2; m++) {
                    int r = wr * 32 + m * 16 + lr;
                    af[m] = *(const s16x8*)(as + r * 64 + (((ks * 4 + lq) ^ (r & 7)) * 8));
                }
                #pragma unroll
                for (int n = 0; n < 2; n++) {
                    int r = wc * 32 + n * 16 + lr;
                    bfv[n] = *(const s16x8*)(bs + r * 64 + (((ks * 4 + lq) ^ (r & 7)) * 8));
                }
                #pragma unroll
                for (int m = 0; m < 2; m++)
                    #pragma unroll
                    for (int n = 0; n < 2; n++)
                        acc[m][n] = __builtin_amdgcn_mfma_f32_16x16x32_bf16(af[m], bfv[n], acc[m][n], 0, 0, 0);
            }
            cur ^= 1;
        }
        #pragma unroll
        for (int m = 0; m < 2; m++)
            #pragma unroll
            for (int n = 0; n < 2; n++)
                #pragma unroll
                for (int j = 0; j < 4; j++) {
                    int lrow = wr * 32 + m * 16 + lq * 4 + j;
                    int lcol = wc * 32 + n * 16 + lr;
                    float v = acc[m][n][j] + bg1[n0 + lcol];
                    v = (v >= 0.f) ? v : 0.2f * v;
                    v = 0.5f * v + 0.5f * x[(size_t)(m0 + lrow) * 512 + n0 + lcol];
                    x1s[lrow * 136 + lcol] = f2bf(v);
                }
        __syncthreads();
        const int i = tid >> 3, cb = tid & 7, c0 = cb * 16;
        const int bi = m0 + i;
        const int r = rid[i];
        float acc2[16] = {};
        #pragma unroll
        for (int m = 0; m < 8; m++) {
            float wm = adjw[(size_t)bi * 8 + m];
            int j = ri[r * 8 + m];
            #pragma unroll
            for (int cc = 0; cc < 2; cc++) {
                s16x8 v = *(const s16x8*)(x1s + j * 136 + c0 + cc * 8);
                #pragma unroll
                for (int t = 0; t < 8; t++) acc2[cc * 8 + t] += wm * bf2f((u16)v[t]);
            }
        }
        #pragma unroll
        for (int cc = 0; cc < 2; cc++) {
            s16x8 o;
            #pragma unroll
            for (int t = 0; t < 8; t++) o[t] = (short)f2bf(acc2[cc * 8 + t]);
            *(s16x8*)(m2_bf + (size_t)bi * 512 + n0 + c0 + cc * 8) = o;
        }
    }
    grid_barrier(bar, tid, NB);

    // ================= P4: out = leaky(m2 @ Wg2 + bg2), fp32 =================
    {
        u16* As = (u16*)sm;                 // [2][4096]
        u16* Bs = (u16*)(sm + 16384);       // [2][4096]
        const int nid = swz256(wg);
        const int m0 = (nid >> 2) * 64, n0 = (nid & 3) * 64;
        const int wr = w >> 1, wc = w & 1;  // 4 x 2 waves, each 16 x 32
        f32x4 acc[2] = {};
        auto stage = [&](int buf, int kt) {
            gload16(m2_bf + (size_t)(m0 + sr) * 512 + kt + gsl * 8, As + buf * 4096 + tid * 8);
            gload16(Wg2t + (size_t)(n0 + sr) * 512 + kt + gsl * 8, Bs + buf * 4096 + tid * 8);
        };
        stage(0, 0);
        int cur = 0;
        for (int t = 0; t < 8; t++) {
            __syncthreads();
            if (t < 7) stage(cur ^ 1, (t + 1) * 64);
            const u16* as = As + cur * 4096;
            const u16* bs = Bs + cur * 4096;
            #pragma unroll
            for (int ks = 0; ks < 2; ks++) {
                int ra = wr * 16 + lr;
                s16x8 af = *(const s16x8*)(as + ra * 64 + (((ks * 4 + lq) ^ (ra & 7)) * 8));
                #pragma unroll
                for (int n = 0; n < 2; n++) {
                    int r = wc * 32 + n * 16 + lr;
                    s16x8 bv = *(const s16x8*)(bs + r * 64 + (((ks * 4 + lq) ^ (r & 7)) * 8));
                    acc[n] = __builtin_amdgcn_mfma_f32_16x16x32_bf16(af, bv, acc[n], 0, 0, 0);
                }
            }
            cur ^= 1;
        }
        #pragma unroll
        for (int n = 0; n < 2; n++)
            #pragma unroll
            for (int j = 0; j < 4; j++) {
                int row = m0 + wr * 16 + lq * 4 + j;
                int col = n0 + wc * 32 + n * 16 + lr;
                float v = acc[n][j] + bg2[col];
                v = (v >= 0.f) ? v : 0.2f * v;
                out[(size_t)row * 256 + col] = v;
            }
    }
}

// ---------------- launch ----------------
extern "C" void kernel_launch(void* const* d_in, const int* in_sizes, int n_in,
                              void* d_out, int out_size, void* d_ws, size_t ws_size,
                              hipStream_t stream) {
    const float* x    = (const float*)d_in[0];
    const float* W1   = (const float*)d_in[1];
    const float* b1   = (const float*)d_in[2];
    const float* W2   = (const float*)d_in[3];
    const float* b2   = (const float*)d_in[4];
    const float* Wg1  = (const float*)d_in[5];
    const float* bg1  = (const float*)d_in[6];
    const float* Wg2  = (const float*)d_in[7];
    const float* bg2  = (const float*)d_in[8];
    const int* region_indices = (const int*)d_in[9];
    float* out = (float*)d_out;

    char* ws = (char*)d_ws;
    const size_t MB = 1024 * 1024;
    u16*   x_bf  = (u16*)(ws);                        // 4 MB
    u16*   W1t   = (u16*)(ws + 4 * MB);               // 1 MB   [1024][512]
    u16*   Wg1t  = (u16*)(ws + 5 * MB);               // 0.5 MB [512][512]
    u16*   Wg2t  = (u16*)(ws + 5 * MB + 512 * 1024);  // 0.25MB [256][512]
    u16*   a_bf  = (u16*)(ws + 6 * MB);               // 4 MB
    u16*   bp_bf = (u16*)(ws + 10 * MB);              // 4 MB
    u16*   m1_bf = (u16*)(ws + 14 * MB);              // 4 MB
    u16*   m2_bf = (u16*)(ws + 18 * MB);              // 4 MB
    float* adjw  = (float*)(ws + 22 * MB);            // 128 KB
    u32*   bar   = (u32*)(ws + 32 * MB);              // grid barrier state

    hipMemsetAsync(bar, 0, 64, stream);               // barrier init (captured)

    fused_kernel<<<256, 512, 0, stream>>>(
        x, W1, b1, W2, b2, Wg1, bg1, Wg2, bg2, region_indices, out,
        x_bf, W1t, Wg1t, Wg2t, a_bf, bp_bf, m1_bf, m2_bf, adjw, bar);
}

// Round 7
// 164.466 us; speedup vs baseline: 1.5894x; 1.5894x over previous
//
#include <hip/hip_runtime.h>
#include <math.h>

typedef __attribute__((ext_vector_type(8))) short s16x8;
typedef __attribute__((ext_vector_type(4))) float f32x4;
typedef unsigned short u16;
typedef unsigned int   u32;

__device__ __forceinline__ float bf2f(u16 u) { return __uint_as_float(((u32)u) << 16); }
__device__ __forceinline__ u16 f2bf(float f) {
    u32 u = __float_as_uint(f);
    return (u16)((u + 0x7FFFu + ((u >> 16) & 1u)) >> 16);
}
__device__ __forceinline__ void gload16(const void* g, void* l) {
    __builtin_amdgcn_global_load_lds((const __attribute__((address_space(1))) u32*)g,
                                     (__attribute__((address_space(3))) u32*)l, 16, 0, 0);
}

// ---------------- prep: x->bf16; W1a,W1b,Wg2 -> Bt[1280][512]; Wg1 -> Wg1t ----
// blocks [0,1024): x cvt | [1024,1536): W1 | [1536,1792): Wg1 | [1792,1920): Wg2
__global__ __launch_bounds__(256)
void prep_kernel(const float* __restrict__ x, u16* __restrict__ x_bf,
                 const float* __restrict__ W1, u16* __restrict__ Bt,
                 const float* __restrict__ Wg1, u16* __restrict__ Wg1t,
                 const float* __restrict__ Wg2)
{
    __shared__ float tile[32][33];
    const int bx = blockIdx.x, tid = threadIdx.x;
    if (bx < 1024) {
        size_t i = ((size_t)bx * 256 + tid) * 8;
        const float4* p = (const float4*)(x + i);
        float4 v0 = p[0], v1 = p[1];
        s16x8 o;
        o[0]=(short)f2bf(v0.x); o[1]=(short)f2bf(v0.y); o[2]=(short)f2bf(v0.z); o[3]=(short)f2bf(v0.w);
        o[4]=(short)f2bf(v1.x); o[5]=(short)f2bf(v1.y); o[6]=(short)f2bf(v1.z); o[7]=(short)f2bf(v1.w);
        *(s16x8*)(x_bf + i) = o;
        return;
    }
    const float* src; u16* dst; int k0, n0, nsrc, obase;
    if (bx < 1536) {                       // W1 half h -> Bt rows [h*512..)
        int idx = bx - 1024, h = idx >> 8, t = idx & 255;
        src = W1 + (size_t)h * 512 * 512; dst = Bt; obase = h * 512;
        k0 = (t >> 4) * 32; n0 = (t & 15) * 32; nsrc = 512;
    } else if (bx < 1792) {                // Wg1 [512x512] -> Wg1t
        int t = bx - 1536;
        src = Wg1; dst = Wg1t; obase = 0;
        k0 = (t >> 4) * 32; n0 = (t & 15) * 32; nsrc = 512;
    } else {                               // Wg2 [512x256] -> Bt rows [1024..1280)
        int t = bx - 1792;
        src = Wg2; dst = Bt; obase = 1024;
        k0 = (t >> 3) * 32; n0 = (t & 7) * 32; nsrc = 256;
    }
    int tx = tid & 31, ty = tid >> 5;
    #pragma unroll
    for (int j = 0; j < 4; j++)
        tile[ty + j * 8][tx] = src[(size_t)(k0 + ty + j * 8) * nsrc + n0 + tx];
    __syncthreads();
    #pragma unroll
    for (int j = 0; j < 4; j++)
        dst[(size_t)(obase + n0 + ty + j * 8) * 512 + k0 + tx] = f2bf(tile[tx][ty + j * 8]);
}

// ---------------- GEMM1: x_bf @ [W1a|W1b|Wg2] = a|bp|u  (M=4096,N=1280,K=512)
// 128x128 tiles, grid (10,32)=320 blocks, 512 thr (8 waves 4Mx2N)
__global__ __launch_bounds__(512)
void gemm1_kernel(const u16* __restrict__ A, const u16* __restrict__ Bt,
                  u16* __restrict__ a_bf, u16* __restrict__ bp_bf, u16* __restrict__ u_bf)
{
    __shared__ __align__(16) u16 As[2][8192];
    __shared__ __align__(16) u16 Bs[2][8192];

    const int tid = threadIdx.x;
    const int lane = tid & 63, w = tid >> 6;
    const int wr = w >> 1, wc = w & 1;
    const int lr = lane & 15, lq = lane >> 4;

    int L = blockIdx.y * 10 + blockIdx.x;          // nwg = 320
    int nid = (L & 7) * 40 + (L >> 3);             // bijective XCD swizzle
    const int by = nid / 10, bx = nid - by * 10;
    const int m0 = by * 128, n0 = bx * 128;

    const int sr = tid >> 3, ss = tid & 7;
    const int gsl = ss ^ (sr & 7);

    f32x4 acc[2][4] = {};

    auto stage = [&](int buf, int kt) {
        #pragma unroll
        for (int ch = 0; ch < 2; ch++)
            gload16(A + (size_t)(m0 + ch * 64 + sr) * 512 + kt + gsl * 8,
                    &As[buf][ch * 4096 + tid * 8]);
        #pragma unroll
        for (int ch = 0; ch < 2; ch++)
            gload16(Bt + (size_t)(n0 + ch * 64 + sr) * 512 + kt + gsl * 8,
                    &Bs[buf][ch * 4096 + tid * 8]);
    };

    stage(0, 0);
    int cur = 0;
    for (int t = 0; t < 8; t++) {
        __syncthreads();
        if (t < 7) stage(cur ^ 1, (t + 1) * 64);
        const u16* as = As[cur]; const u16* bs = Bs[cur];
        #pragma unroll
        for (int ks = 0; ks < 2; ks++) {
            s16x8 af[2], bfv[4];
            #pragma unroll
            for (int m = 0; m < 2; m++) {
                int r = wr * 32 + m * 16 + lr;
                af[m] = *(const s16x8*)(as + r * 64 + (((ks * 4 + lq) ^ (r & 7)) * 8));
            }
            #pragma unroll
            for (int n = 0; n < 4; n++) {
                int r = wc * 64 + n * 16 + lr;
                bfv[n] = *(const s16x8*)(bs + r * 64 + (((ks * 4 + lq) ^ (r & 7)) * 8));
            }
            #pragma unroll
            for (int m = 0; m < 2; m++)
                #pragma unroll
                for (int n = 0; n < 4; n++)
                    acc[m][n] = __builtin_amdgcn_mfma_f32_16x16x32_bf16(af[m], bfv[n], acc[m][n], 0, 0, 0);
        }
        cur ^= 1;
    }

    #pragma unroll
    for (int m = 0; m < 2; m++)
        #pragma unroll
        for (int n = 0; n < 4; n++)
            #pragma unroll
            for (int j = 0; j < 4; j++) {
                int row = m0 + wr * 32 + m * 16 + lq * 4 + j;
                int col = n0 + wc * 64 + n * 16 + lr;
                u16 v = f2bf(acc[m][n][j]);
                if (col < 512)       a_bf [(size_t)row * 512 + col] = v;
                else if (col < 1024) bp_bf[(size_t)row * 512 + col - 512] = v;
                else                 u_bf [(size_t)row * 256 + col - 1024] = v;
            }
}

// ---------------- tail: per-batch scores -> m1 -> y1 -> z -> out -------------
// 64 blocks (one per batch) x 512 thr. All intermediates in LDS.
#define LDW 520   // padded LDS row stride (elems); 1040 B rows: 16B-aligned, 2-way banks

__global__ __launch_bounds__(512)
void tail_kernel(const u16* __restrict__ a_bf, const u16* __restrict__ bp_bf,
                 const u16* __restrict__ x_bf, const u16* __restrict__ u_bf,
                 const float* __restrict__ b1, const float* __restrict__ W2,
                 const float* __restrict__ b2,
                 const u16* __restrict__ Wg1t, const u16* __restrict__ Wg2t,
                 const float* __restrict__ bg1, const float* __restrict__ bg2,
                 const int* __restrict__ region_indices, float* __restrict__ out)
{
    __shared__ __align__(16) u16 bufA[64 * LDW];   // bp (linear 512) -> y1 (LDW)
    __shared__ __align__(16) u16 bufB[64 * LDW];   // m1 (LDW) -> w (LDW)
    __shared__ __align__(16) u16 Bsm[2][4096];     // 8 KB B-tile double buffer
    __shared__ float adjS[64][8];
    __shared__ int ri[64], rid[64];

    const int b = blockIdx.x, tid = threadIdx.x;
    const int lane = tid & 63, w = tid >> 6;
    const int lr = lane & 15, lq = lane >> 4;
    const int sr = tid >> 3, ss = tid & 7, gsl = ss ^ (sr & 7);

    // stage bp[b] -> bufA linear [64][512]
    #pragma unroll
    for (int it = 0; it < 8; it++)
        gload16(bp_bf + (size_t)b * 32768 + it * 4096 + tid * 8, bufA + it * 4096 + tid * 8);
    if (tid < 64) { int c = region_indices[tid]; ri[tid] = c; rid[c] = tid >> 3; }

    const int d0 = lane * 8;
    float4 b1a = *(const float4*)(b1 + d0), b1b = *(const float4*)(b1 + d0 + 4);
    float4 w2a = *(const float4*)(W2 + d0), w2b = *(const float4*)(W2 + d0 + 4);
    float b1v[8] = { b1a.x, b1a.y, b1a.z, b1a.w, b1b.x, b1b.y, b1b.z, b1b.w };
    float w2v[8] = { w2a.x, w2a.y, w2a.z, w2a.w, w2b.x, w2b.y, w2b.z, w2b.w };
    const float bias2 = b2[0];
    __syncthreads();

    // ---- scores + softmax + m1 (8 waves x 8 rows) ----
    for (int rr = 0; rr < 8; rr++) {
        const int i = w * 8 + rr;
        const int bi = b * 64 + i;
        const int r = rid[i];
        int mem[8];
        #pragma unroll
        for (int m = 0; m < 8; m++) mem[m] = ri[r * 8 + m];

        s16x8 a8 = *(const s16x8*)(a_bf + (size_t)bi * 512 + d0);
        float ai[8];
        #pragma unroll
        for (int t = 0; t < 8; t++) ai[t] = bf2f((u16)a8[t]) + b1v[t];

        float p[8];
        #pragma unroll
        for (int m = 0; m < 8; m++) {
            s16x8 bv = *(const s16x8*)(bufA + mem[m] * 512 + d0);
            float s = 0.f;
            #pragma unroll
            for (int t = 0; t < 8; t++) {
                float h = ai[t] + bf2f((u16)bv[t]);
                s += fmaxf(h, 0.f) * w2v[t];
            }
            p[m] = s;
        }
        #pragma unroll
        for (int off = 32; off >= 1; off >>= 1)
            #pragma unroll
            for (int m = 0; m < 8; m++) p[m] += __shfl_xor(p[m], off);

        float scmax = -INFINITY;
        #pragma unroll
        for (int m = 0; m < 8; m++) {
            p[m] = (mem[m] == i) ? -INFINITY : p[m] + bias2;
            scmax = fmaxf(scmax, p[m]);
        }
        float esum = 0.f;
        #pragma unroll
        for (int m = 0; m < 8; m++) {
            p[m] = (mem[m] == i) ? 0.f : __expf(p[m] - scmax);
            esum += p[m];
        }
        const float inv = 1.f / esum;

        float accv[8] = {};
        #pragma unroll
        for (int m = 0; m < 8; m++) {
            p[m] *= inv;
            s16x8 xv = *(const s16x8*)(x_bf + ((size_t)(b * 64 + mem[m])) * 512 + d0);
            #pragma unroll
            for (int t = 0; t < 8; t++) accv[t] += p[m] * bf2f((u16)xv[t]);
        }
        s16x8 o;
        #pragma unroll
        for (int t = 0; t < 8; t++) o[t] = (short)f2bf(accv[t]);
        *(s16x8*)(bufB + i * LDW + d0) = o;          // m1 -> LDS (padded)
        if (lane < 8) adjS[i][lane] = p[lane];
    }
    __syncthreads();

    // ---- y1 = leaky(m1 @ Wg1^T + bg1) -> bufA [64][LDW] ----
    {
        const int wr = w >> 1, wc = w & 1;           // 4 x 2 waves: 16 rows x 32 cols
        f32x4 acc[2] = {};
        auto stageB = [&](int buf, int step) {       // step: nc=step>>3, kt=step&7
            int nc = step >> 3, kt = step & 7;
            gload16(Wg1t + (size_t)(nc * 64 + sr) * 512 + kt * 64 + gsl * 8,
                    &Bsm[buf][tid * 8]);
        };
        stageB(0, 0);
        int cur = 0;
        for (int step = 0; step < 64; step++) {
            __syncthreads();
            if (step < 63) stageB(cur ^ 1, step + 1);
            const int kt = step & 7;
            const u16* bs = Bsm[cur];
            #pragma unroll
            for (int ks = 0; ks < 2; ks++) {
                int ra = wr * 16 + lr;
                s16x8 af = *(const s16x8*)(bufB + ra * LDW + kt * 64 + ks * 32 + lq * 8);
                #pragma unroll
                for (int n = 0; n < 2; n++) {
                    int rb = wc * 32 + n * 16 + lr;
                    s16x8 bv = *(const s16x8*)(bs + rb * 64 + (((ks * 4 + lq) ^ (rb & 7)) * 8));
                    acc[n] = __builtin_amdgcn_mfma_f32_16x16x32_bf16(af, bv, acc[n], 0, 0, 0);
                }
            }
            if (kt == 7) {
                int nc = step >> 3;
                #pragma unroll
                for (int n = 0; n < 2; n++)
                    #pragma unroll
                    for (int j = 0; j < 4; j++) {
                        int row = wr * 16 + lq * 4 + j;
                        int col = nc * 64 + wc * 32 + n * 16 + lr;
                        float v = acc[n][j] + bg1[col];
                        v = (v >= 0.f) ? v : 0.2f * v;
                        bufA[row * LDW + col] = f2bf(v);
                    }
                acc[0] = (f32x4){0.f, 0.f, 0.f, 0.f};
                acc[1] = (f32x4){0.f, 0.f, 0.f, 0.f};
            }
            cur ^= 1;
        }
    }
    __syncthreads();

    // ---- w = 0.5*(y1 @ Wg2^T) + 0.5*u -> bufB [64][LDW] (cols 0..255) ----
    {
        const int wr = w >> 1, wc = w & 1;
        f32x4 acc[2] = {};
        auto stageC = [&](int buf, int step) {       // 32 steps: nc=step>>3 (0..3)
            int nc = step >> 3, kt = step & 7;
            gload16(Wg2t + (size_t)(nc * 64 + sr) * 512 + kt * 64 + gsl * 8,
                    &Bsm[buf][tid * 8]);
        };
        stageC(0, 0);
        int cur = 0;
        for (int step = 0; step < 32; step++) {
            __syncthreads();
            if (step < 31) stageC(cur ^ 1, step + 1);
            const int kt = step & 7;
            const u16* bs = Bsm[cur];
            #pragma unroll
            for (int ks = 0; ks < 2; ks++) {
                int ra = wr * 16 + lr;
                s16x8 af = *(const s16x8*)(bufA + ra * LDW + kt * 64 + ks * 32 + lq * 8);
                #pragma unroll
                for (int n = 0; n < 2; n++) {
                    int rb = wc * 32 + n * 16 + lr;
                    s16x8 bv = *(const s16x8*)(bs + rb * 64 + (((ks * 4 + lq) ^ (rb & 7)) * 8));
                    acc[n] = __builtin_amdgcn_mfma_f32_16x16x32_bf16(af, bv, acc[n], 0, 0, 0);
                }
            }
            if (kt == 7) {
                int nc = step >> 3;
                #pragma unroll
                for (int n = 0; n < 2; n++)
                    #pragma unroll
                    for (int j = 0; j < 4; j++) {
                        int row = wr * 16 + lq * 4 + j;
                        int col = nc * 64 + wc * 32 + n * 16 + lr;
                        float v = 0.5f * acc[n][j]
                                + 0.5f * bf2f(u_bf[(size_t)(b * 64 + row) * 256 + col]);
                        bufB[row * LDW + col] = f2bf(v);
                    }
                acc[0] = (f32x4){0.f, 0.f, 0.f, 0.f};
                acc[1] = (f32x4){0.f, 0.f, 0.f, 0.f};
            }
            cur ^= 1;
        }
    }
    __syncthreads();

    // ---- out[bi] = leaky(adj @ w + bg2), fp32 ----
    {
        const int i = tid >> 3, c0 = (tid & 7) * 32;
        const int r = rid[i];
        float accv[32] = {};
        #pragma unroll
        for (int m = 0; m < 8; m++) {
            float wm = adjS[i][m];
            int j = ri[r * 8 + m];
            #pragma unroll
            for (int t4 = 0; t4 < 4; t4++) {
                s16x8 v = *(const s16x8*)(bufB + j * LDW + c0 + t4 * 8);
                #pragma unroll
                for (int e = 0; e < 8; e++) accv[t4 * 8 + e] += wm * bf2f((u16)v[e]);
            }
        }
        float* orow = out + (size_t)(b * 64 + i) * 256 + c0;
        #pragma unroll
        for (int t4 = 0; t4 < 8; t4++) {
            float4 o;
            float* a4 = accv + t4 * 4;
            o.x = a4[0] + bg2[c0 + t4 * 4 + 0]; o.x = (o.x >= 0.f) ? o.x : 0.2f * o.x;
            o.y = a4[1] + bg2[c0 + t4 * 4 + 1]; o.y = (o.y >= 0.f) ? o.y : 0.2f * o.y;
            o.z = a4[2] + bg2[c0 + t4 * 4 + 2]; o.z = (o.z >= 0.f) ? o.z : 0.2f * o.z;
            o.w = a4[3] + bg2[c0 + t4 * 4 + 3]; o.w = (o.w >= 0.f) ? o.w : 0.2f * o.w;
            *(float4*)(orow + t4 * 4) = o;
        }
    }
}

// ---------------- launch ----------------
extern "C" void kernel_launch(void* const* d_in, const int* in_sizes, int n_in,
                              void* d_out, int out_size, void* d_ws, size_t ws_size,
                              hipStream_t stream) {
    const float* x    = (const float*)d_in[0];
    const float* W1   = (const float*)d_in[1];
    const float* b1   = (const float*)d_in[2];
    const float* W2   = (const float*)d_in[3];
    const float* b2   = (const float*)d_in[4];
    const float* Wg1  = (const float*)d_in[5];
    const float* bg1  = (const float*)d_in[6];
    const float* Wg2  = (const float*)d_in[7];
    const float* bg2  = (const float*)d_in[8];
    const int* region_indices = (const int*)d_in[9];
    float* out = (float*)d_out;

    char* ws = (char*)d_ws;
    const size_t MB = 1024 * 1024;
    u16* x_bf  = (u16*)(ws);                 // 4 MB
    u16* Bt    = (u16*)(ws + 4 * MB);        // 1.25 MB  [1280][512]
    u16* Wg1t  = (u16*)(ws + 6 * MB);        // 0.5 MB   [512][512]
    u16* a_bf  = (u16*)(ws + 8 * MB);        // 4 MB
    u16* bp_bf = (u16*)(ws + 12 * MB);       // 4 MB
    u16* u_bf  = (u16*)(ws + 16 * MB);       // 2 MB     [4096][256]

    prep_kernel<<<1920, 256, 0, stream>>>(x, x_bf, W1, Bt, Wg1, Wg1t, Wg2);

    // a | bp | u = x @ [W1a | W1b | Wg2]   (M=4096, N=1280, K=512)
    gemm1_kernel<<<dim3(10, 32), 512, 0, stream>>>(x_bf, Bt, a_bf, bp_bf, u_bf);

    // per-batch: scores -> m1 -> y1 -> z -> out
    tail_kernel<<<64, 512, 0, stream>>>(a_bf, bp_bf, x_bf, u_bf, b1, W2, b2,
                                        Wg1t, Bt + (size_t)1024 * 512, bg1, bg2,
                                        region_indices, out);
}

// Round 8
// 117.953 us; speedup vs baseline: 2.2161x; 1.3943x over previous
//
#include <hip/hip_runtime.h>
#include <math.h>

typedef __attribute__((ext_vector_type(8))) short s16x8;
typedef __attribute__((ext_vector_type(4))) float f32x4;
typedef unsigned short u16;
typedef unsigned int   u32;

__device__ __forceinline__ float bf2f(u16 u) { return __uint_as_float(((u32)u) << 16); }
__device__ __forceinline__ u16 f2bf(float f) {
    u32 u = __float_as_uint(f);
    return (u16)((u + 0x7FFFu + ((u >> 16) & 1u)) >> 16);
}
__device__ __forceinline__ void gload16(const void* g, void* l) {
    __builtin_amdgcn_global_load_lds((const __attribute__((address_space(1))) u32*)g,
                                     (__attribute__((address_space(3))) u32*)l, 16, 0, 0);
}
// bijective XCD swizzle: nwg multiple of 8; nx a power of 2
__device__ __forceinline__ void xcd_swz(int& bx, int& by) {
    int nx = (int)gridDim.x;
    int L = bx + by * nx;
    int nwg = nx * (int)gridDim.y;
    int nid = (L & 7) * (nwg >> 3) + (L >> 3);
    bx = nid & (nx - 1);
    by = nid / nx;
}

// ---------------- prep: x->bf16; W1 -> W1t[1024][512]; Wg1t; Wg2t ----------
// blocks [0,1024): x cvt | [1024,1536): W1 | [1536,1792): Wg1 | [1792,1920): Wg2
__global__ __launch_bounds__(256)
void prep_kernel(const float* __restrict__ x, u16* __restrict__ x_bf,
                 const float* __restrict__ W1, u16* __restrict__ W1t,
                 const float* __restrict__ Wg1, u16* __restrict__ Wg1t,
                 const float* __restrict__ Wg2, u16* __restrict__ Wg2t)
{
    __shared__ float tile[32][33];
    const int bx = blockIdx.x, tid = threadIdx.x;
    if (bx < 1024) {
        size_t i = ((size_t)bx * 256 + tid) * 8;
        const float4* p = (const float4*)(x + i);
        float4 v0 = p[0], v1 = p[1];
        s16x8 o;
        o[0]=(short)f2bf(v0.x); o[1]=(short)f2bf(v0.y); o[2]=(short)f2bf(v0.z); o[3]=(short)f2bf(v0.w);
        o[4]=(short)f2bf(v1.x); o[5]=(short)f2bf(v1.y); o[6]=(short)f2bf(v1.z); o[7]=(short)f2bf(v1.w);
        *(s16x8*)(x_bf + i) = o;
        return;
    }
    const float* src; u16* dst; int k0, n0, nsrc, obase;
    if (bx < 1536) {                       // W1 half h -> W1t rows [h*512..)
        int idx = bx - 1024, h = idx >> 8, t = idx & 255;
        src = W1 + (size_t)h * 512 * 512; dst = W1t; obase = h * 512;
        k0 = (t >> 4) * 32; n0 = (t & 15) * 32; nsrc = 512;
    } else if (bx < 1792) {                // Wg1 [512x512]
        int t = bx - 1536;
        src = Wg1; dst = Wg1t; obase = 0;
        k0 = (t >> 4) * 32; n0 = (t & 15) * 32; nsrc = 512;
    } else {                               // Wg2 [512x256]
        int t = bx - 1792;
        src = Wg2; dst = Wg2t; obase = 0;
        k0 = (t >> 3) * 32; n0 = (t & 7) * 32; nsrc = 256;
    }
    int tx = tid & 31, ty = tid >> 5;
    #pragma unroll
    for (int j = 0; j < 4; j++)
        tile[ty + j * 8][tx] = src[(size_t)(k0 + ty + j * 8) * nsrc + n0 + tx];
    __syncthreads();
    #pragma unroll
    for (int j = 0; j < 4; j++)
        dst[(size_t)(obase + n0 + ty + j * 8) * 512 + k0 + tx] = f2bf(tile[tx][ty + j * 8]);
}

// ---------------- GEMM1: a|bp = x @ [W1a|W1b]  (M=4096,N=1024,K=512) --------
// 128x128 tiles, grid (8,32), 512 thr (8 waves 4Mx2N)
__global__ __launch_bounds__(512)
void gemm1_kernel(const u16* __restrict__ A, const u16* __restrict__ Bt,
                  u16* __restrict__ a_bf, u16* __restrict__ bp_bf)
{
    __shared__ __align__(16) u16 As[2][8192];
    __shared__ __align__(16) u16 Bs[2][8192];

    const int tid = threadIdx.x;
    const int lane = tid & 63, w = tid >> 6;
    const int wr = w >> 1, wc = w & 1;
    const int lr = lane & 15, lq = lane >> 4;
    int bx = blockIdx.x, by = blockIdx.y;
    xcd_swz(bx, by);
    const int m0 = by * 128, n0 = bx * 128;

    const int sr = tid >> 3, ss = tid & 7;
    const int gsl = ss ^ (sr & 7);

    f32x4 acc[2][4] = {};

    auto stage = [&](int buf, int kt) {
        #pragma unroll
        for (int ch = 0; ch < 2; ch++)
            gload16(A + (size_t)(m0 + ch * 64 + sr) * 512 + kt + gsl * 8,
                    &As[buf][ch * 4096 + tid * 8]);
        #pragma unroll
        for (int ch = 0; ch < 2; ch++)
            gload16(Bt + (size_t)(n0 + ch * 64 + sr) * 512 + kt + gsl * 8,
                    &Bs[buf][ch * 4096 + tid * 8]);
    };

    stage(0, 0);
    int cur = 0;
    for (int t = 0; t < 8; t++) {
        __syncthreads();
        if (t < 7) stage(cur ^ 1, (t + 1) * 64);
        const u16* as = As[cur]; const u16* bs = Bs[cur];
        #pragma unroll
        for (int ks = 0; ks < 2; ks++) {
            s16x8 af[2], bfv[4];
            #pragma unroll
            for (int m = 0; m < 2; m++) {
                int r = wr * 32 + m * 16 + lr;
                af[m] = *(const s16x8*)(as + r * 64 + (((ks * 4 + lq) ^ (r & 7)) * 8));
            }
            #pragma unroll
            for (int n = 0; n < 4; n++) {
                int r = wc * 64 + n * 16 + lr;
                bfv[n] = *(const s16x8*)(bs + r * 64 + (((ks * 4 + lq) ^ (r & 7)) * 8));
            }
            #pragma unroll
            for (int m = 0; m < 2; m++)
                #pragma unroll
                for (int n = 0; n < 4; n++)
                    acc[m][n] = __builtin_amdgcn_mfma_f32_16x16x32_bf16(af[m], bfv[n], acc[m][n], 0, 0, 0);
        }
        cur ^= 1;
    }

    #pragma unroll
    for (int m = 0; m < 2; m++)
        #pragma unroll
        for (int n = 0; n < 4; n++)
            #pragma unroll
            for (int j = 0; j < 4; j++) {
                int row = m0 + wr * 32 + m * 16 + lq * 4 + j;
                int col = n0 + wc * 64 + n * 16 + lr;
                u16 v = f2bf(acc[m][n][j]);
                if (col < 512) a_bf [(size_t)row * 512 + col] = v;
                else           bp_bf[(size_t)row * 512 + col - 512] = v;
            }
}

// ---------------- scores_v2: member-only staging -----------------------------
// 256 blocks x 256 thr. Block (b,q) handles regions 2q,2q+1 (16 rows).
// Stages exactly the 16 bp member rows + 16 x member rows (32 KB LDS).
__global__ __launch_bounds__(256)
void scores_kernel(const u16* __restrict__ a_bf, const u16* __restrict__ bp_bf,
                   const u16* __restrict__ x_bf,
                   const float* __restrict__ b1, const float* __restrict__ W2,
                   const float* __restrict__ b2,
                   const int* __restrict__ region_indices,
                   float* __restrict__ adjw, u16* __restrict__ m1_bf)
{
    __shared__ __align__(16) u16 bpL[16 * 512];   // 16 KB
    __shared__ __align__(16) u16 xL[16 * 512];    // 16 KB
    __shared__ int memS[16];

    int L = blockIdx.x;
    int nid = ((L & 7) << 5) + (L >> 3);          // XCD-contiguous
    const int b = nid >> 2, q = nid & 3;
    const int tid = threadIdx.x, lane = tid & 63, w = tid >> 6;

    if (tid < 16) memS[tid] = region_indices[q * 16 + tid];
    __syncthreads();

    #pragma unroll
    for (int it = 0; it < 4; it++) {
        int rl = it * 4 + w;                       // local row 0..15, one per wave
        size_t src = (size_t)(b * 64 + memS[rl]) * 512 + lane * 8;
        gload16(bp_bf + src, bpL + rl * 512 + lane * 8);
        gload16(x_bf  + src, xL  + rl * 512 + lane * 8);
    }

    const int d0 = lane * 8;
    float4 b1a = *(const float4*)(b1 + d0), b1b = *(const float4*)(b1 + d0 + 4);
    float4 w2a = *(const float4*)(W2 + d0), w2b = *(const float4*)(W2 + d0 + 4);
    float b1v[8] = { b1a.x, b1a.y, b1a.z, b1a.w, b1b.x, b1b.y, b1b.z, b1b.w };
    float w2v[8] = { w2a.x, w2a.y, w2a.z, w2a.w, w2b.x, w2b.y, w2b.z, w2b.w };
    const float bias2 = b2[0];
    __syncthreads();                               // staging complete

    for (int rr = 0; rr < 4; rr++) {
        const int rl = w * 4 + rr;                 // local row
        const int rhalf = rl >> 3, s_slot = rl & 7;
        const int i = memS[rl];                    // channel id
        const int bi = b * 64 + i;

        s16x8 a8 = *(const s16x8*)(a_bf + (size_t)bi * 512 + d0);
        float ai[8];
        #pragma unroll
        for (int t = 0; t < 8; t++) ai[t] = bf2f((u16)a8[t]) + b1v[t];

        float p[8];
        #pragma unroll
        for (int m = 0; m < 8; m++) {
            s16x8 bv = *(const s16x8*)(bpL + (rhalf * 8 + m) * 512 + d0);
            float s = 0.f;
            #pragma unroll
            for (int t = 0; t < 8; t++) {
                float h = ai[t] + bf2f((u16)bv[t]);
                s += fmaxf(h, 0.f) * w2v[t];
            }
            p[m] = s;
        }
        #pragma unroll
        for (int off = 32; off >= 1; off >>= 1)
            #pragma unroll
            for (int m = 0; m < 8; m++) p[m] += __shfl_xor(p[m], off);

        float scmax = -INFINITY;
        #pragma unroll
        for (int m = 0; m < 8; m++) {
            p[m] = (m == s_slot) ? -INFINITY : p[m] + bias2;
            scmax = fmaxf(scmax, p[m]);
        }
        float esum = 0.f;
        #pragma unroll
        for (int m = 0; m < 8; m++) {
            p[m] = (m == s_slot) ? 0.f : __expf(p[m] - scmax);
            esum += p[m];
        }
        const float inv = 1.f / esum;

        float accv[8] = {};
        #pragma unroll
        for (int m = 0; m < 8; m++) {
            p[m] *= inv;
            s16x8 xv = *(const s16x8*)(xL + (rhalf * 8 + m) * 512 + d0);
            #pragma unroll
            for (int t = 0; t < 8; t++) accv[t] += p[m] * bf2f((u16)xv[t]);
        }
        s16x8 o;
        #pragma unroll
        for (int t = 0; t < 8; t++) o[t] = (short)f2bf(accv[t]);
        *(s16x8*)(m1_bf + (size_t)bi * 512 + d0) = o;
        if (lane < 8) adjw[(size_t)bi * 8 + lane] = p[lane];
    }
}

// ---------------- GEMM2 + fused m2: m2 = 0.5*adj@y1 + 0.5*m1 ----------------
// BM=64 (one batch), BN=128, 512 thr. y1 = leaky(m1@Wg1+bg1) kept in LDS.
__global__ __launch_bounds__(512)
void gemm2_m2_kernel(const u16* __restrict__ A, const u16* __restrict__ Bt,
                     const float* __restrict__ bias,
                     const float* __restrict__ adjw, const int* __restrict__ region_indices,
                     u16* __restrict__ m2)
{
    __shared__ __align__(16) u16 As[2][4096];
    __shared__ __align__(16) u16 Bs[2][8192];
    __shared__ __align__(16) u16 y1s[64 * 136];
    __shared__ int ri[64], rid[64];

    const int tid = threadIdx.x;
    const int lane = tid & 63, w = tid >> 6;
    const int wr = w >> 2, wc = w & 3;             // 2 x 4 waves
    const int lr = lane & 15, lq = lane >> 4;
    int bx = blockIdx.x, by = blockIdx.y;
    xcd_swz(bx, by);
    const int b = by, n0 = bx * 128, m0 = b * 64;

    const int sr = tid >> 3, ss = tid & 7, gsl = ss ^ (sr & 7);

    if (tid < 64) { int c = region_indices[tid]; ri[tid] = c; rid[c] = tid >> 3; }

    f32x4 acc[2][2] = {};

    auto stage = [&](int buf, int kt) {
        gload16(A + (size_t)(m0 + sr) * 512 + kt + gsl * 8, &As[buf][tid * 8]);
        #pragma unroll
        for (int ch = 0; ch < 2; ch++)
            gload16(Bt + (size_t)(n0 + ch * 64 + sr) * 512 + kt + gsl * 8,
                    &Bs[buf][ch * 4096 + tid * 8]);
    };

    stage(0, 0);
    int cur = 0;
    for (int t = 0; t < 8; t++) {
        __syncthreads();
        if (t < 7) stage(cur ^ 1, (t + 1) * 64);
        const u16* as = As[cur]; const u16* bs = Bs[cur];
        #pragma unroll
        for (int ks = 0; ks < 2; ks++) {
            s16x8 af[2], bfv[2];
            #pragma unroll
            for (int m = 0; m < 2; m++) {
                int r = wr * 32 + m * 16 + lr;
                af[m] = *(const s16x8*)(as + r * 64 + (((ks * 4 + lq) ^ (r & 7)) * 8));
            }
            #pragma unroll
            for (int n = 0; n < 2; n++) {
                int r = wc * 32 + n * 16 + lr;
                bfv[n] = *(const s16x8*)(bs + r * 64 + (((ks * 4 + lq) ^ (r & 7)) * 8));
            }
            #pragma unroll
            for (int m = 0; m < 2; m++)
                #pragma unroll
                for (int n = 0; n < 2; n++)
                    acc[m][n] = __builtin_amdgcn_mfma_f32_16x16x32_bf16(af[m], bfv[n], acc[m][n], 0, 0, 0);
        }
        cur ^= 1;
    }

    // epilogue 1: y1 = leaky(acc + bg1) -> LDS
    #pragma unroll
    for (int m = 0; m < 2; m++)
        #pragma unroll
        for (int n = 0; n < 2; n++)
            #pragma unroll
            for (int j = 0; j < 4; j++) {
                int lrow = wr * 32 + m * 16 + lq * 4 + j;
                int lcol = wc * 32 + n * 16 + lr;
                float v = acc[m][n][j] + bias[n0 + lcol];
                v = (v >= 0.f) ? v : 0.2f * v;
                y1s[lrow * 136 + lcol] = f2bf(v);
            }
    __syncthreads();

    // epilogue 2: m2[i,:] = 0.5 * sum_m adj[bi,m]*y1[j_m,:] + 0.5 * m1[i,:]
    const int i = tid >> 3, cb = tid & 7, c0 = cb * 16;
    const int bi = m0 + i;
    const int r = rid[i];
    float acc2[16] = {};
    #pragma unroll
    for (int m = 0; m < 8; m++) {
        float wm = adjw[(size_t)bi * 8 + m];
        int j = ri[r * 8 + m];
        #pragma unroll
        for (int cc = 0; cc < 2; cc++) {
            s16x8 v = *(const s16x8*)(y1s + j * 136 + c0 + cc * 8);
            #pragma unroll
            for (int t = 0; t < 8; t++) acc2[cc * 8 + t] += wm * bf2f((u16)v[t]);
        }
    }
    #pragma unroll
    for (int cc = 0; cc < 2; cc++) {
        s16x8 m1v = *(const s16x8*)(A + (size_t)bi * 512 + n0 + c0 + cc * 8);
        s16x8 o;
        #pragma unroll
        for (int t = 0; t < 8; t++)
            o[t] = (short)f2bf(0.5f * acc2[cc * 8 + t] + 0.5f * bf2f((u16)m1v[t]));
        *(s16x8*)(m2 + (size_t)bi * 512 + n0 + c0 + cc * 8) = o;
    }
}

// ---------------- GEMM3: out = leaky(m2@Wg2+bg2), 64x64, fp32 out ----------
__global__ __launch_bounds__(256)
void gemm3_kernel(const u16* __restrict__ A, const u16* __restrict__ Bt,
                  const float* __restrict__ bias, float* __restrict__ Of)
{
    __shared__ __align__(16) u16 As[2][4096];
    __shared__ __align__(16) u16 Bs[2][4096];

    const int tid = threadIdx.x;
    const int lane = tid & 63, w = tid >> 6;
    const int wr = w >> 1, wc = w & 1;
    const int lr = lane & 15, lq = lane >> 4;
    int bx = blockIdx.x, by = blockIdx.y;
    xcd_swz(bx, by);
    const int m0 = by * 64, n0 = bx * 64;

    const int sr = tid >> 3, ss = tid & 7, gsl = ss ^ (sr & 7);

    f32x4 acc[2][2] = {};

    auto stage = [&](int buf, int kt) {
        #pragma unroll
        for (int ch = 0; ch < 2; ch++)
            gload16(A + (size_t)(m0 + ch * 32 + sr) * 512 + kt + gsl * 8,
                    &As[buf][ch * 2048 + tid * 8]);
        #pragma unroll
        for (int ch = 0; ch < 2; ch++)
            gload16(Bt + (size_t)(n0 + ch * 32 + sr) * 512 + kt + gsl * 8,
                    &Bs[buf][ch * 2048 + tid * 8]);
    };

    stage(0, 0);
    int cur = 0;
    for (int t = 0; t < 8; t++) {
        __syncthreads();
        if (t < 7) stage(cur ^ 1, (t + 1) * 64);
        const u16* as = As[cur]; const u16* bs = Bs[cur];
        #pragma unroll
        for (int ks = 0; ks < 2; ks++) {
            s16x8 af[2], bfv[2];
            #pragma unroll
            for (int m = 0; m < 2; m++) {
                int r = wr * 32 + m * 16 + lr;
                af[m] = *(const s16x8*)(as + r * 64 + (((ks * 4 + lq) ^ (r & 7)) * 8));
            }
            #pragma unroll
            for (int n = 0; n < 2; n++) {
                int r = wc * 32 + n * 16 + lr;
                bfv[n] = *(const s16x8*)(bs + r * 64 + (((ks * 4 + lq) ^ (r & 7)) * 8));
            }
            #pragma unroll
            for (int m = 0; m < 2; m++)
                #pragma unroll
                for (int n = 0; n < 2; n++)
                    acc[m][n] = __builtin_amdgcn_mfma_f32_16x16x32_bf16(af[m], bfv[n], acc[m][n], 0, 0, 0);
        }
        cur ^= 1;
    }

    #pragma unroll
    for (int m = 0; m < 2; m++)
        #pragma unroll
        for (int n = 0; n < 2; n++)
            #pragma unroll
            for (int j = 0; j < 4; j++) {
                int row = m0 + wr * 32 + m * 16 + lq * 4 + j;
                int col = n0 + wc * 32 + n * 16 + lr;
                float v = acc[m][n][j] + bias[col];
                v = (v >= 0.f) ? v : 0.2f * v;
                Of[(size_t)row * 256 + col] = v;
            }
}

// ---------------- launch ----------------
extern "C" void kernel_launch(void* const* d_in, const int* in_sizes, int n_in,
                              void* d_out, int out_size, void* d_ws, size_t ws_size,
                              hipStream_t stream) {
    const float* x    = (const float*)d_in[0];
    const float* W1   = (const float*)d_in[1];
    const float* b1   = (const float*)d_in[2];
    const float* W2   = (const float*)d_in[3];
    const float* b2   = (const float*)d_in[4];
    const float* Wg1  = (const float*)d_in[5];
    const float* bg1  = (const float*)d_in[6];
    const float* Wg2  = (const float*)d_in[7];
    const float* bg2  = (const float*)d_in[8];
    const int* region_indices = (const int*)d_in[9];
    float* out = (float*)d_out;

    char* ws = (char*)d_ws;
    const size_t MB = 1024 * 1024;
    u16* x_bf  = (u16*)(ws);                        // 4 MB
    u16* W1t   = (u16*)(ws + 4 * MB);               // 1 MB   [1024][512]
    u16* Wg1t  = (u16*)(ws + 5 * MB);               // 0.5 MB [512][512]
    u16* Wg2t  = (u16*)(ws + 5 * MB + 512 * 1024);  // 0.25MB [256][512]
    u16* a_bf  = (u16*)(ws + 6 * MB);               // 4 MB
    u16* bp_bf = (u16*)(ws + 10 * MB);              // 4 MB
    u16* m1_bf = (u16*)(ws + 14 * MB);              // 4 MB
    u16* m2_bf = (u16*)(ws + 18 * MB);              // 4 MB
    float* adjw = (float*)(ws + 22 * MB);           // 128 KB

    prep_kernel<<<1920, 256, 0, stream>>>(x, x_bf, W1, W1t, Wg1, Wg1t, Wg2, Wg2t);

    // a | bp = x @ [W1a|W1b]  (M=4096, N=1024, K=512)
    gemm1_kernel<<<dim3(8, 32), 512, 0, stream>>>(x_bf, W1t, a_bf, bp_bf);

    // scores + softmax + m1 (member-only staging)
    scores_kernel<<<256, 256, 0, stream>>>(a_bf, bp_bf, x_bf, b1, W2, b2,
                                           region_indices, adjw, m1_bf);

    // y1 (LDS) + m2 = 0.5*adj@y1 + 0.5*m1
    gemm2_m2_kernel<<<dim3(4, 64), 512, 0, stream>>>(
        m1_bf, Wg1t, bg1, adjw, region_indices, m2_bf);

    // out = leaky(m2@Wg2+bg2), fp32
    gemm3_kernel<<<dim3(4, 64), 256, 0, stream>>>(m2_bf, Wg2t, bg2, out);
}